// Round 6
// baseline (260.649 us; speedup 1.0000x reference)
//
#include <hip/hip_runtime.h>
#include <hip/hip_bf16.h>

#define NN 100000
#define NE 800000
#define HIDDEN 128
#define NED (2 * NE)            // edge-directions: [0,NE)=fwd(by src), [NE,2NE)=bwd(by dst)
#define BKN 64                  // nodes per bucket (bucket covers BOTH directions)
#define NBF 1563                // ceil(NN/BKN)
#define NBUCK NBF               // 1563 buckets, 128 virtual nodes each (dir*64+tl)
#define PS 7                    // buckets per thread in part_scatter scan (7*256>=1563)
#define CHUNK 4096              // edges per partition block
#define PBLK ((NED + CHUNK - 1) / CHUNK)   // 391

typedef __attribute__((ext_vector_type(8))) short bf16x8;
typedef __attribute__((ext_vector_type(4))) short bf16x4;
typedef __attribute__((ext_vector_type(4))) float f32x4;

__device__ __forceinline__ short f2bf(float f) {
  union { float f; unsigned u; } x; x.f = f;
  unsigned r = x.u + 0x7fffu + ((x.u >> 16) & 1u);   // RNE
  return (short)(r >> 16);
}
__device__ __forceinline__ float bf2f(short s) {
  union { unsigned u; float f; } x;
  x.u = ((unsigned)(unsigned short)s) << 16;
  return x.f;
}

// ---- weights fp32 -> bf16 (order: [0]=Ws_w, [1]=W_w, [2]=Wt_w) ----
__global__ __launch_bounds__(256) void convert_weights(
    const float* __restrict__ m0, const float* __restrict__ m1,
    const float* __restrict__ m2, short* __restrict__ out) {
  int i = blockIdx.x * 256 + threadIdx.x;   // [0, 3*16384)
  int m = i >> 14, j = i & 16383;
  const float* s = (m == 0) ? m0 : (m == 1) ? m1 : m2;
  out[i] = f2bf(s[j]);
}

// ---- h fp32 -> bf16 (vectorized; NN*HIDDEN = 12.8M, /4 = 3.2M threads exact) ----
__global__ __launch_bounds__(256) void convert_h(
    const float* __restrict__ h, short* __restrict__ h_bf) {
  int i = blockIdx.x * 256 + threadIdx.x;
  f32x4 v = *(const f32x4*)(h + (size_t)i * 4);
  bf16x4 o;
#pragma unroll
  for (int j = 0; j < 4; j++) o[j] = f2bf(v[j]);
  *(bf16x4*)(h_bf + (size_t)i * 4) = o;
}

// ---- 1. global bucket histogram (LDS-aggregated) ----
__global__ __launch_bounds__(256) void part_count(
    const int* __restrict__ esrc, const int* __restrict__ edst,
    int* __restrict__ ghist) {
  __shared__ int lh[NBUCK];
  int tid = threadIdx.x;
  for (int i = tid; i < NBUCK; i += 256) lh[i] = 0;
  __syncthreads();
  int base = blockIdx.x * CHUNK;
  int nit = min(CHUNK, NED - base);
  for (int k = tid; k < nit; k += 256) {
    int ed = base + k;
    int b = (ed < NE) ? (esrc[ed] >> 6) : (edst[ed - NE] >> 6);
    atomicAdd(&lh[b], 1);
  }
  __syncthreads();
  for (int i = tid; i < NBUCK; i += 256) {
    int c = lh[i];
    if (c) atomicAdd(ghist + i, c);
  }
}

// ---- 2. exclusive scan over ghist[NBUCK] -> bstart + gcur (shfl-based) ----
__global__ __launch_bounds__(1024) void bucket_scan(
    const int* __restrict__ ghist, int* __restrict__ bstart,
    int* __restrict__ gcur) {
  __shared__ int wsum[16];
  __shared__ int woff[16];
  int tid = threadIdx.x;
  int lane = tid & 63, wv = tid >> 6;
  int base = tid * 4;                       // 1024*4 = 4096 >= NBUCK
  int v0 = (base + 0 < NBUCK) ? ghist[base + 0] : 0;
  int v1 = (base + 1 < NBUCK) ? ghist[base + 1] : 0;
  int v2 = (base + 2 < NBUCK) ? ghist[base + 2] : 0;
  int v3 = (base + 3 < NBUCK) ? ghist[base + 3] : 0;
  int s = v0 + v1 + v2 + v3;
  int inc = s;                              // wave-inclusive scan of s
#pragma unroll
  for (int d = 1; d < 64; d <<= 1) {
    int t = __shfl_up(inc, d, 64);
    if (lane >= d) inc += t;
  }
  if (lane == 63) wsum[wv] = inc;
  __syncthreads();
  if (wv == 0) {
    int x = (lane < 16) ? wsum[lane] : 0;
    int i2 = x;
#pragma unroll
    for (int d = 1; d < 16; d <<= 1) {
      int t = __shfl_up(i2, d, 64);
      if (lane >= d) i2 += t;
    }
    if (lane < 16) woff[lane] = i2 - x;     // exclusive wave offset
  }
  __syncthreads();
  int e = woff[wv] + inc - s;               // exclusive prefix for base+0
  if (base + 0 < NBUCK) { bstart[base + 0] = e; gcur[base + 0] = e; }
  e += v0;
  if (base + 1 < NBUCK) { bstart[base + 1] = e; gcur[base + 1] = e; }
  e += v1;
  if (base + 2 < NBUCK) { bstart[base + 2] = e; gcur[base + 2] = e; }
  e += v2;
  if (base + 3 < NBUCK) { bstart[base + 3] = e; gcur[base + 3] = e; }
  e += v3;
  if (tid == 1023) bstart[NBUCK] = e;       // grand total == NED
}

// ---- 3. radix partition: scatter through LDS, write coalesced runs to ELP ----
// ELP item: (dir<<23) | (tgt_local<<17) | nbr   -> vn = pv>>17 in [0,128)
__global__ __launch_bounds__(256) void part_scatter(
    const int* __restrict__ esrc, const int* __restrict__ edst,
    int* __restrict__ gcur, unsigned* __restrict__ ELP) {
  __shared__ int lcur[NBUCK];     // counts, then mutable scatter cursors
  __shared__ int loff[NBUCK];     // block-local exclusive offsets (kept intact)
  __shared__ int gbase[NBUCK];    // claimed global run starts
  __shared__ int psum[256];
  __shared__ unsigned buf[CHUNK]; // 16 KB staging
  __shared__ unsigned short bidA[CHUNK];  // 8 KB bucket-id per slot
  int tid = threadIdx.x;
  for (int i = tid; i < NBUCK; i += 256) lcur[i] = 0;
  __syncthreads();
  int base = blockIdx.x * CHUNK;
  int nit = min(CHUNK, NED - base);
  // pass 1: local count (into lcur)
  for (int k = tid; k < nit; k += 256) {
    int ed = base + k;
    int b = (ed < NE) ? (esrc[ed] >> 6) : (edst[ed - NE] >> 6);
    atomicAdd(&lcur[b], 1);
  }
  __syncthreads();
  // local exclusive scan (PS buckets per thread; PS*256 >= NBUCK)
  int s = 0;
  int lo0 = tid * PS, hi0 = min(NBUCK, tid * PS + PS);
  for (int j = lo0; j < hi0; j++) s += lcur[j];
  psum[tid] = s;
  __syncthreads();
  for (int off = 1; off < 256; off <<= 1) {
    int x = psum[tid];
    int add = (tid >= off) ? psum[tid - off] : 0;
    __syncthreads();
    psum[tid] = x + add;
    __syncthreads();
  }
  int run = psum[tid] - s;
  for (int j = lo0; j < hi0; j++) { loff[j] = run; run += lcur[j]; }
  __syncthreads();
  // claim global runs + convert lcur count -> cursor (each b owned by 1 thread)
  for (int b = tid; b < NBUCK; b += 256) {
    int c = lcur[b];
    if (c) gbase[b] = atomicAdd(gcur + b, c);
    lcur[b] = loff[b];
  }
  __syncthreads();
  // pass 2: scatter into LDS staging, record bucket id per slot
  for (int k = tid; k < nit; k += 256) {
    int ed = base + k;
    int b, tl, nbr, dir;
    if (ed < NE) { int tg = esrc[ed]; nbr = edst[ed]; b = tg >> 6; tl = tg & 63; dir = 0; }
    else { int e = ed - NE; int tg = edst[e]; nbr = esrc[e]; b = tg >> 6; tl = tg & 63; dir = 1; }
    int slot = atomicAdd(&lcur[b], 1);
    buf[slot] = ((unsigned)dir << 23) | ((unsigned)tl << 17) | (unsigned)nbr;
    bidA[slot] = (unsigned short)b;
  }
  __syncthreads();
  // sweep: consecutive lanes -> consecutive slots -> bucket-contiguous global runs
  for (int i = tid; i < nit; i += 256) {
    int b = bidA[i];
    ELP[gbase[b] + (i - loff[b])] = buf[i];
  }
}

// ---- 4. FUSED gather + GEMM per 64-node range ----
// Phase A: counting-sort the block's ~1024 edge-directions by vn=dir*64+tl,
//          stage h rows into At[0].
// Phase B: register-pipelined gather (r2's proven 4-deep quarter-wave loop,
//          32 qw x 4 vns) -> agg rows written to At[1](fwd)/At[2](bwd) in LDS.
// Phase C: 8-wave MFMA epilogue (M=64 tile): out = relu(h@Ws^T + aggF@W^T
//          + aggB@Wt^T + biases + degF*W_b + degB*Wt_b), deg from cnt[] LDS.
// aggF/aggB/degFB never touch HBM (saves ~104 MB round-trip).
#define ACC8(V) { a0f+=bf2f((V)[0]); a1f+=bf2f((V)[1]); a2f+=bf2f((V)[2]); a3f+=bf2f((V)[3]); \
                  a4f+=bf2f((V)[4]); a5f+=bf2f((V)[5]); a6f+=bf2f((V)[6]); a7f+=bf2f((V)[7]); }
#define MACC8(M,V) { a0f=fmaf(M,bf2f((V)[0]),a0f); a1f=fmaf(M,bf2f((V)[1]),a1f); \
                     a2f=fmaf(M,bf2f((V)[2]),a2f); a3f=fmaf(M,bf2f((V)[3]),a3f); \
                     a4f=fmaf(M,bf2f((V)[4]),a4f); a5f=fmaf(M,bf2f((V)[5]),a5f); \
                     a6f=fmaf(M,bf2f((V)[6]),a6f); a7f=fmaf(M,bf2f((V)[7]),a7f); }
__global__ __launch_bounds__(512, 4) void fused_gather_gemm(
    const short* __restrict__ h_bf, const unsigned* __restrict__ ELP,
    const int* __restrict__ bstart, const short* __restrict__ Wbf,
    const float* __restrict__ Wb, const float* __restrict__ Wsb,
    const float* __restrict__ Wtb, float* __restrict__ out) {
  __shared__ int sorted[2048];   // n ~ Poisson(1024), +5 sigma ~ 1184 << 2048
  __shared__ int cnt[128];
  __shared__ int pfx[128];
  __shared__ int cur[128];
  __shared__ short At[3 * 64 * 136];  // 52,224 B; [0]=h [1]=aggF [2]=aggB
  int tid = threadIdx.x;
  int blk = blockIdx.x;
  int node0 = blk * BKN;
  int s = bstart[blk], e = bstart[blk + 1], n = e - s;
  if (tid < 128) cnt[tid] = 0;
  __syncthreads();
  for (int k = tid; k < n; k += 512) atomicAdd(&cnt[ELP[s + k] >> 17], 1);
  // stage h rows (independent of cnt; overlaps histogram latency)
  for (int p = tid; p < 1024; p += 512) {
    int row = p >> 4, colc = p & 15;
    int nd = node0 + row;
    bf16x8 hv = {0, 0, 0, 0, 0, 0, 0, 0};
    if (nd < NN) hv = *(const bf16x8*)(h_bf + (size_t)nd * HIDDEN + colc * 8);
    *(bf16x8*)(At + row * 136 + colc * 8) = hv;
  }
  __syncthreads();
  // inclusive scan of cnt -> pfx
  int v = (tid < 128) ? cnt[tid] : 0;
  if (tid < 128) pfx[tid] = v;
  __syncthreads();
  for (int off = 1; off < 128; off <<= 1) {
    int add = (tid < 128 && tid >= off) ? pfx[tid - off] : 0;
    __syncthreads();
    if (tid < 128) pfx[tid] += add;
    __syncthreads();
  }
  if (tid < 128) cur[tid] = pfx[tid] - cnt[tid];   // exclusive start
  __syncthreads();
  // scatter into sorted-by-vn LDS array (store nbr only)
  for (int k = tid; k < n; k += 512) {
    unsigned pv = ELP[s + k];
    int slot = atomicAdd(&cur[pv >> 17], 1);
    sorted[slot] = (int)(pv & 0x1FFFFu);
  }
  __syncthreads();
  // Phase B: gather. 32 quarter-waves, 4 vns each, 4-deep row pipeline.
  int qw = tid >> 4, q = tid & 15;
  const short* hb = h_bf + (size_t)q * 8;      // lane's 16B column slice
#pragma unroll
  for (int t = 0; t < 4; t++) {
    int nd = qw * 4 + t;                       // vn in [0,128)
    int b0 = pfx[nd];
    int deg = cnt[nd];
    int a0 = b0 - deg;
    float a0f = 0.f, a1f = 0.f, a2f = 0.f, a3f = 0.f;
    float a4f = 0.f, a5f = 0.f, a6f = 0.f, a7f = 0.f;
    if (deg > 0) {
      int lastp = b0 - 1;
      int i0 = sorted[a0];
      int i1 = sorted[min(a0 + 1, lastp)];
      int i2 = sorted[min(a0 + 2, lastp)];
      int i3 = sorted[min(a0 + 3, lastp)];
      bf16x8 v0 = *(const bf16x8*)(hb + (size_t)i0 * HIDDEN);
      bf16x8 v1 = *(const bf16x8*)(hb + (size_t)i1 * HIDDEN);
      bf16x8 v2 = *(const bf16x8*)(hb + (size_t)i2 * HIDDEN);
      bf16x8 v3 = *(const bf16x8*)(hb + (size_t)i3 * HIDDEN);
      int j = a0;
      int ni0 = sorted[min(j + 4, lastp)];
      int ni1 = sorted[min(j + 5, lastp)];
      int ni2 = sorted[min(j + 6, lastp)];
      int ni3 = sorted[min(j + 7, lastp)];
      while (j + 4 <= b0) {
        ACC8(v0); v0 = *(const bf16x8*)(hb + (size_t)ni0 * HIDDEN);
        ACC8(v1); v1 = *(const bf16x8*)(hb + (size_t)ni1 * HIDDEN);
        ACC8(v2); v2 = *(const bf16x8*)(hb + (size_t)ni2 * HIDDEN);
        ACC8(v3); v3 = *(const bf16x8*)(hb + (size_t)ni3 * HIDDEN);
        j += 4;
        ni0 = sorted[min(j + 4, lastp)];
        ni1 = sorted[min(j + 5, lastp)];
        ni2 = sorted[min(j + 6, lastp)];
        ni3 = sorted[min(j + 7, lastp)];
      }
      int r = b0 - j;   // 0..3 remaining; v0..v2 hold edges j..j+2 (clamped dups)
      float m1 = (r > 0) ? 1.f : 0.f;
      float m2 = (r > 1) ? 1.f : 0.f;
      float m3 = (r > 2) ? 1.f : 0.f;
      MACC8(m1, v0); MACC8(m2, v1); MACC8(m3, v2);
    }
    // write agg row to LDS: mat = 1+dir, row = tl, cols q*8..q*8+7
    short* dst = At + (1 + (nd >> 6)) * 8704 + (nd & 63) * 136 + q * 8;
    bf16x8 o;
    o[0] = f2bf(a0f); o[1] = f2bf(a1f); o[2] = f2bf(a2f); o[3] = f2bf(a3f);
    o[4] = f2bf(a4f); o[5] = f2bf(a5f); o[6] = f2bf(a6f); o[7] = f2bf(a7f);
    *(bf16x8*)dst = o;
  }
  __syncthreads();
  // Phase C: MFMA epilogue. 8 waves; wave owns cols [w*16, w*16+16).
  int lane = tid & 63;
  int m16 = lane & 15;
  int kq  = lane >> 4;
  int col0 = (tid >> 6) * 16;
  bf16x8 wf[3][4];
#pragma unroll
  for (int i = 0; i < 3; i++)
#pragma unroll
    for (int t = 0; t < 4; t++)
      wf[i][t] = *(const bf16x8*)(Wbf + i * 16384 + (col0 + m16) * 128 + t * 32 + kq * 8);
  f32x4 bW = *(const f32x4*)(Wb  + col0 + kq * 4);
  f32x4 bS = *(const f32x4*)(Wsb + col0 + kq * 4);
  f32x4 bT = *(const f32x4*)(Wtb + col0 + kq * 4);
#pragma unroll
  for (int g = 0; g < 4; g++) {
    f32x4 acc = {0.f, 0.f, 0.f, 0.f};
    const short* lb = At + (g * 16 + m16) * 136 + kq * 8;
#pragma unroll
    for (int i = 0; i < 3; i++)
#pragma unroll
      for (int t = 0; t < 4; t++) {
        bf16x8 af = *(const bf16x8*)(lb + i * 8704 + t * 32);
        acc = __builtin_amdgcn_mfma_f32_16x16x32_bf16(wf[i][t], af, acc, 0, 0, 0);
      }
    int rl = g * 16 + m16;
    int r = node0 + rl;
    if (r < NN) {
      float dF = (float)cnt[rl];
      float dB = (float)cnt[64 + rl];
      f32x4 vv;
#pragma unroll
      for (int j = 0; j < 4; j++)
        vv[j] = fmaxf(acc[j] + bS[j] + dF * bW[j] + dB * bT[j], 0.f);
      *(f32x4*)(out + (size_t)r * HIDDEN + col0 + kq * 4) = vv;
    }
  }
}

extern "C" void kernel_launch(void* const* d_in, const int* in_sizes, int n_in,
                              void* d_out, int out_size, void* d_ws, size_t ws_size,
                              hipStream_t stream) {
  const float* h    = (const float*)d_in[0];
  const int*   esrc = (const int*)d_in[1];
  const int*   edst = (const int*)d_in[2];
  const float* Ww   = (const float*)d_in[3];
  const float* Wb   = (const float*)d_in[4];
  const float* Wsw  = (const float*)d_in[5];
  const float* Wsb  = (const float*)d_in[6];
  const float* Wtw  = (const float*)d_in[7];
  const float* Wtb  = (const float*)d_in[8];
  float* out = (float*)d_out;

  char* ws = (char*)d_ws;
  // byte layout (NBUCK=1563)
  int*      ghist  = (int*)(ws + 0);             //     6,252
  int*      bstart = (int*)(ws + 6272);          //     6,256
  int*      gcur   = (int*)(ws + 12544);         //     6,252  (ends 18,796)
  unsigned* ELP    = (unsigned*)(ws + 18816);    // 6,400,000  (ends 6,418,816)
  short*    Wbf    = (short*)(ws + 6418816);     //    98,304  (ends 6,517,120)
  short*    h_bf   = (short*)(ws + 6517120);     // 25,600,000 (ends 32,117,120)

  hipMemsetAsync(ghist, 0, NBUCK * sizeof(int), stream);

  convert_weights<<<192, 256, 0, stream>>>(Wsw, Ww, Wtw, Wbf);
  convert_h<<<12500, 256, 0, stream>>>(h, h_bf);
  part_count<<<PBLK, 256, 0, stream>>>(esrc, edst, ghist);
  bucket_scan<<<1, 1024, 0, stream>>>(ghist, bstart, gcur);
  part_scatter<<<PBLK, 256, 0, stream>>>(esrc, edst, gcur, ELP);
  fused_gather_gemm<<<NBF, 512, 0, stream>>>(
      h_bf, ELP, bstart, Wbf, Wb, Wsb, Wtb, out);
}